// Round 2
// baseline (600.211 us; speedup 1.0000x reference)
//
#include <hip/hip_runtime.h>

#define NUM_P 16320
#define NUM_C 21
#define THETA 0.01f

// ---------------- Kernel A: per-anchor losses + pos mask ----------------
__global__ __launch_bounds__(256) void anchor_kernel(
    const float* __restrict__ loc, const float* __restrict__ conf,
    const float* __restrict__ arm, const float* __restrict__ loct,
    const int* __restrict__ conft,
    int* __restrict__ num_pos, float* __restrict__ rankvals,
    float* __restrict__ partial_l, float* __restrict__ partial_c, int total)
{
    __shared__ float tile[256 * NUM_C];
    __shared__ float red_l[4], red_c[4];
    const int tid = threadIdx.x;
    const int base = blockIdx.x * 256;

    // coalesced float4 stage of the 21-float conf rows (block chunk = 21504 B, 16B-aligned)
    {
        const float4* conf4 = (const float4*)(conf + (size_t)base * NUM_C);
        float4* tile4 = (float4*)tile;
        #pragma unroll
        for (int i = tid; i < 256 * NUM_C / 4; i += 256)
            tile4[i] = conf4[i];
    }
    __syncthreads();

    const int a = base + tid;
    float ll = 0.f, cep = 0.f;
    bool pos = false;
    int b = 0;
    if (a < total) {
        b = a / NUM_P;                      // wave-uniform: NUM_P % 64 == 0
        const int t = conft[a];
        const float* cf = &tile[tid * NUM_C];  // stride 21 -> conflict-free
        float mx = cf[0];
        #pragma unroll
        for (int j = 1; j < NUM_C; ++j) mx = fmaxf(mx, cf[j]);
        float s = 0.f;
        #pragma unroll
        for (int j = 0; j < NUM_C; ++j) s += __expf(cf[j] - mx);
        const float ce = mx + __logf(s) - cf[t];

        const float2 av = ((const float2*)arm)[a];
        const float am = fmaxf(av.x, av.y);
        const float e0 = __expf(av.x - am), e1 = __expf(av.y - am);
        const float p1 = e1 / (e0 + e1);
        pos = (t > 0) && (p1 > THETA);

        if (pos) {
            cep = ce;
            #pragma unroll
            for (int j = 0; j < 4; ++j) {
                float d = loc[4 * a + j] - loct[4 * a + j];
                float ad = fabsf(d);
                ll += (ad < 1.f) ? 0.5f * ad * ad : ad - 0.5f;
            }
        }
        rankvals[a] = pos ? 0.f : ce;       // loss_for_rank
    }

    // wave-level reduce; ONE atomic per wave for num_pos (64 addrs, ~255 hits each)
    unsigned long long pm = __ballot(pos);
    #pragma unroll
    for (int off = 32; off > 0; off >>= 1) {
        ll  += __shfl_down(ll, off, 64);
        cep += __shfl_down(cep, off, 64);
    }
    const int lane = tid & 63, w = tid >> 6;
    if (lane == 0) {
        red_l[w] = ll;
        red_c[w] = cep;
        int cnt = (int)__popcll(pm);
        if (cnt) atomicAdd(&num_pos[b], cnt);
    }
    __syncthreads();
    // atomic-free global partials: one slot per block
    if (tid == 0) {
        partial_l[blockIdx.x] = red_l[0] + red_l[1] + red_l[2] + red_l[3];
        partial_c[blockIdx.x] = red_c[0] + red_c[1] + red_c[2] + red_c[3];
    }
}

// ---------------- Kernel B: per-row radix-select top-k sum ----------------
// values are all >= 0 (lse - true_logit >= 0) so unsigned bit order == float order.
__global__ __launch_bounds__(256) void select_kernel(
    const float* __restrict__ rankvals, const int* __restrict__ num_pos,
    float* __restrict__ accum)
{
    const int b = blockIdx.x;
    const float* row = rankvals + (size_t)b * NUM_P;
    const int tid = threadIdx.x;
    const int lane = tid & 63;

    __shared__ int hist[256];
    __shared__ unsigned s_prefix;
    __shared__ int s_kk;
    __shared__ float wsum[4];

    int k = min(3 * num_pos[b], NUM_P - 1);
    if (k <= 0) return;  // uniform across block

    unsigned prefix = 0;
    unsigned himask = 0;
    int kk = k;

    for (int pass = 0; pass < 4; ++pass) {
        const int shift = 24 - 8 * pass;
        hist[tid] = 0;
        __syncthreads();
        // ballot-aggregated histogram: one LDS atomic per DISTINCT bin per wave-iter
        for (int i = tid; i < NUM_P; i += 256) {
            unsigned u = __float_as_uint(row[i]);
            bool part = (u & himask) == prefix;
            unsigned bin = part ? ((u >> shift) & 255u) : 0xFFFFFFFFu;
            unsigned long long alive = __ballot(part);
            while (alive) {
                int leader = __ffsll((unsigned long long)alive) - 1;
                unsigned lb = __shfl(bin, leader, 64);
                unsigned long long mm = __ballot(bin == lb);
                if (lane == leader) atomicAdd(&hist[lb], (int)__popcll(mm));
                alive &= ~mm;
            }
        }
        __syncthreads();
        if (tid == 0) {
            int cum = 0;
            for (int j = 255; j >= 0; --j) {
                int c = hist[j];
                if (cum + c >= kk) {
                    s_kk = kk - cum;
                    s_prefix = prefix | ((unsigned)j << shift);
                    break;
                }
                cum += c;
            }
        }
        __syncthreads();
        prefix = s_prefix;
        kk = s_kk;
        himask |= (0xFFu << shift);
        __syncthreads();
    }

    const unsigned vbits = prefix;      // k-th largest value (bits)
    const float v = __uint_as_float(vbits);

    float partial = 0.f;
    for (int i = tid; i < NUM_P; i += 256) {
        float x = row[i];
        if (__float_as_uint(x) > vbits) partial += x;
    }
    #pragma unroll
    for (int off = 32; off > 0; off >>= 1)
        partial += __shfl_down(partial, off, 64);
    if (lane == 0) wsum[tid >> 6] = partial;
    __syncthreads();
    if (tid == 0) {
        float tot = wsum[0] + wsum[1] + wsum[2] + wsum[3];
        // ties at v contribute kk * v (tie-break by index doesn't change the sum)
        atomicAdd(&accum[2], tot + (float)kk * v);   // only 64 atomics total
    }
}

// ---------------- Kernel C: reduce partials + finalize ----------------
__global__ __launch_bounds__(256) void finalize_kernel(
    const float* __restrict__ accum, const int* __restrict__ num_pos,
    const float* __restrict__ partial_l, const float* __restrict__ partial_c,
    int nblocks, int Bn, float* __restrict__ out)
{
    __shared__ float sl[4], sc[4];
    __shared__ int sn[4];
    const int tid = threadIdx.x;
    float l = 0.f, c = 0.f;
    for (int i = tid; i < nblocks; i += 256) { l += partial_l[i]; c += partial_c[i]; }
    int np = 0;
    for (int i = tid; i < Bn; i += 256) np += num_pos[i];
    #pragma unroll
    for (int off = 32; off > 0; off >>= 1) {
        l  += __shfl_down(l, off, 64);
        c  += __shfl_down(c, off, 64);
        np += __shfl_down(np, off, 64);
    }
    if ((tid & 63) == 0) { sl[tid >> 6] = l; sc[tid >> 6] = c; sn[tid >> 6] = np; }
    __syncthreads();
    if (tid == 0) {
        float L = sl[0] + sl[1] + sl[2] + sl[3];
        float C = sc[0] + sc[1] + sc[2] + sc[3];
        float N = (float)(sn[0] + sn[1] + sn[2] + sn[3]);
        out[0] = L / N;
        out[1] = (C + accum[2]) / N;
    }
}

extern "C" void kernel_launch(void* const* d_in, const int* in_sizes, int n_in,
                              void* d_out, int out_size, void* d_ws, size_t ws_size,
                              hipStream_t stream) {
    const float* loc  = (const float*)d_in[0];
    const float* conf = (const float*)d_in[1];
    const float* arm  = (const float*)d_in[2];
    const float* loct = (const float*)d_in[3];
    const int*  conft = (const int*)d_in[4];
    float* out = (float*)d_out;

    const int total = in_sizes[4];          // B * P
    const int Bn = total / NUM_P;
    const int grid = (total + 255) / 256;

    // ws layout:
    // [0,64):    float accum[16]          (accum[2] = topk sum)
    // [64,1024): int num_pos[B]
    // [1024, +grid*4):            partial_l
    // [1024+32768, +grid*4):      partial_c
    // [1024+65536, ...):          rankvals
    float* accum    = (float*)d_ws;
    int*   num_pos  = (int*)((char*)d_ws + 64);
    float* partial_l = (float*)((char*)d_ws + 1024);
    float* partial_c = (float*)((char*)d_ws + 1024 + 32768);
    float* rankvals  = (float*)((char*)d_ws + 1024 + 65536);

    hipMemsetAsync(d_ws, 0, 1024, stream);

    hipLaunchKernelGGL(anchor_kernel, dim3(grid), dim3(256), 0, stream,
                       loc, conf, arm, loct, conft, num_pos, rankvals,
                       partial_l, partial_c, total);
    hipLaunchKernelGGL(select_kernel, dim3(Bn), dim3(256), 0, stream,
                       rankvals, num_pos, accum);
    hipLaunchKernelGGL(finalize_kernel, dim3(1), dim3(256), 0, stream,
                       accum, num_pos, partial_l, partial_c, grid, Bn, out);
}

// Round 4
// 315.270 us; speedup vs baseline: 1.9038x; 1.9038x over previous
//
#include <hip/hip_runtime.h>

#define NUM_P 16320
#define NUM_C 21
#define THETA 0.01f

// ---------------- Kernel A: per-anchor losses + pos mask ----------------
__global__ __launch_bounds__(256) void anchor_kernel(
    const float* __restrict__ loc, const float* __restrict__ conf,
    const float* __restrict__ arm, const float* __restrict__ loct,
    const int* __restrict__ conft,
    int* __restrict__ num_pos, float* __restrict__ rankvals,
    float* __restrict__ partial_l, float* __restrict__ partial_c, int total)
{
    __shared__ float tile[256 * NUM_C];   // 21504 B
    __shared__ float red_l[4], red_c[4];
    const int tid = threadIdx.x;
    const int base = blockIdx.x * 256;
    const int a = base + tid;

    // hoist small per-anchor loads so they overlap the staging loads
    int t = 0; float2 av = make_float2(0.f, 0.f);
    if (a < total) {
        t = conft[a];
        av = ((const float2*)arm)[a];
    }

    // register-buffered staging: all 6 float4 loads issued before any LDS write
    {
        const float4* conf4 = (const float4*)(conf + (size_t)base * NUM_C);
        const int lim = min(256 * NUM_C / 4, ((total - base) * NUM_C) / 4); // 1344 full
        float4 r[6];
        #pragma unroll
        for (int it = 0; it < 6; ++it) {
            int i = tid + it * 256;
            if (i < lim) r[it] = conf4[i];
        }
        float4* tile4 = (float4*)tile;
        #pragma unroll
        for (int it = 0; it < 6; ++it) {
            int i = tid + it * 256;
            if (i < lim) tile4[i] = r[it];
        }
    }
    __syncthreads();

    float ll = 0.f, cep = 0.f;
    bool pos = false;
    int b = 0;
    if (a < total) {
        b = a / NUM_P;                         // row index (waves never straddle rows)
        const float* cf = &tile[tid * NUM_C];  // stride 21 -> conflict-free
        float mx = cf[0];
        #pragma unroll
        for (int j = 1; j < NUM_C; ++j) mx = fmaxf(mx, cf[j]);
        float s = 0.f;
        #pragma unroll
        for (int j = 0; j < NUM_C; ++j) s += __expf(cf[j] - mx);
        const float ce = mx + __logf(s) - cf[t];

        const float am = fmaxf(av.x, av.y);
        const float e0 = __expf(av.x - am), e1 = __expf(av.y - am);
        const float p1 = e1 / (e0 + e1);
        pos = (t > 0) && (p1 > THETA);

        if (pos) {
            cep = ce;
            const float4 lv = ((const float4*)loc)[a];
            const float4 tv = ((const float4*)loct)[a];
            const float dx[4] = { lv.x - tv.x, lv.y - tv.y, lv.z - tv.z, lv.w - tv.w };
            #pragma unroll
            for (int j = 0; j < 4; ++j) {
                float ad = fabsf(dx[j]);
                ll += (ad < 1.f) ? 0.5f * ad * ad : ad - 0.5f;
            }
        }
        rankvals[a] = pos ? 0.f : ce;          // loss_for_rank
    }

    // wave-level reduce; ONE atomic per wave for num_pos
    unsigned long long pm = __ballot(pos);
    #pragma unroll
    for (int off = 32; off > 0; off >>= 1) {
        ll  += __shfl_down(ll, off, 64);
        cep += __shfl_down(cep, off, 64);
    }
    const int lane = tid & 63, w = tid >> 6;
    if (lane == 0) {
        red_l[w] = ll;
        red_c[w] = cep;
        int cnt = (int)__popcll(pm);
        if (cnt) atomicAdd(&num_pos[b], cnt);
    }
    __syncthreads();
    if (tid == 0) {
        partial_l[blockIdx.x] = red_l[0] + red_l[1] + red_l[2] + red_l[3];
        partial_c[blockIdx.x] = red_c[0] + red_c[1] + red_c[2] + red_c[3];
    }
}

// ---------------- Kernel B: per-row radix-select top-k sum (LDS-resident) ----
// all values >= 0 so unsigned bit order == float order.
__global__ __launch_bounds__(1024) void select_kernel(
    const float* __restrict__ rankvals, const int* __restrict__ num_pos,
    float* __restrict__ topk)
{
    __shared__ float data[NUM_P];          // 65280 B
    __shared__ int hist[256];
    __shared__ unsigned s_prefix;
    __shared__ int s_kk;
    __shared__ float wsum[16];

    const int b = blockIdx.x;
    const int tid = threadIdx.x;
    const int lane = tid & 63;

    // stage row into LDS with register buffering (4 outstanding float4/thread)
    {
        const float4* row4 = (const float4*)(rankvals + (size_t)b * NUM_P);
        float4 r[4];
        #pragma unroll
        for (int it = 0; it < 4; ++it) {
            int i = tid + it * 1024;
            if (i < NUM_P / 4) r[it] = row4[i];
        }
        float4* d4 = (float4*)data;
        #pragma unroll
        for (int it = 0; it < 4; ++it) {
            int i = tid + it * 1024;
            if (i < NUM_P / 4) d4[i] = r[it];
        }
    }
    const int k = min(3 * num_pos[b], NUM_P - 1);
    __syncthreads();
    if (k <= 0) return;   // block-uniform; topk[b] stays 0 from memset

    unsigned prefix = 0, himask = 0;
    int kk = k;

    #pragma unroll
    for (int pass = 0; pass < 4; ++pass) {
        const int shift = 24 - 8 * pass;
        if (tid < 256) hist[tid] = 0;
        __syncthreads();

        if (pass == 0) {
            // ballot-aggregated: CE exponents concentrate into ~3 bins ->
            // ~3 leader iterations per wave-chunk, one LDS atomic per distinct bin
            for (int it = 0; it < 16; ++it) {
                const int i = tid + it * 1024;
                const bool part = i < NUM_P;
                const unsigned u = part ? __float_as_uint(data[i]) : 0u;
                const unsigned bin = u >> 24;
                unsigned long long alive = __ballot(part);
                while (alive) {
                    const int leader = __ffsll(alive) - 1;
                    const unsigned lb = __shfl(bin, leader, 64);
                    const unsigned long long mm = __ballot(part && (bin == lb));
                    if (lane == leader) atomicAdd(&hist[lb], (int)__popcll(mm));
                    alive &= ~mm;
                }
            }
        } else {
            // later passes: participants sparse/spread -> plain LDS atomics
            for (int it = 0; it < 16; ++it) {
                const int i = tid + it * 1024;
                if (i < NUM_P) {
                    const unsigned u = __float_as_uint(data[i]);
                    if ((u & himask) == prefix)
                        atomicAdd(&hist[(u >> shift) & 255u], 1);
                }
            }
        }
        __syncthreads();
        if (tid == 0) {
            int cum = 0;
            for (int j = 255; j >= 0; --j) {
                const int c = hist[j];
                if (cum + c >= kk) {
                    s_kk = kk - cum;
                    s_prefix = prefix | ((unsigned)j << shift);
                    break;
                }
                cum += c;
            }
        }
        __syncthreads();
        prefix = s_prefix;
        kk = s_kk;
        himask |= (0xFFu << shift);
    }

    const unsigned vbits = prefix;       // k-th largest value (bits)
    const float v = __uint_as_float(vbits);

    float partial = 0.f;
    for (int it = 0; it < 16; ++it) {
        const int i = tid + it * 1024;
        if (i < NUM_P) {
            const float x = data[i];
            if (__float_as_uint(x) > vbits) partial += x;
        }
    }
    #pragma unroll
    for (int off = 32; off > 0; off >>= 1)
        partial += __shfl_down(partial, off, 64);
    if (lane == 0) wsum[tid >> 6] = partial;
    __syncthreads();
    if (tid == 0) {
        float tot = 0.f;
        #pragma unroll
        for (int wv = 0; wv < 16; ++wv) tot += wsum[wv];
        // ties at v contribute kk * v (tie-break by index doesn't change the sum)
        topk[b] = tot + (float)kk * v;
    }
}

// ---------------- Kernel C: reduce partials + finalize ----------------
__global__ __launch_bounds__(256) void finalize_kernel(
    const float* __restrict__ topk, const int* __restrict__ num_pos,
    const float* __restrict__ partial_l, const float* __restrict__ partial_c,
    int nblocks, int Bn, float* __restrict__ out)
{
    __shared__ float sl[4], sc[4];
    __shared__ int sn[4];
    const int tid = threadIdx.x;
    float l = 0.f, c = 0.f;
    for (int i = tid; i < nblocks; i += 256) { l += partial_l[i]; c += partial_c[i]; }
    int np = 0;
    for (int i = tid; i < Bn; i += 256) np += num_pos[i];
    float tk = 0.f;
    for (int i = tid; i < Bn; i += 256) tk += topk[i];
    c += tk;
    #pragma unroll
    for (int off = 32; off > 0; off >>= 1) {
        l  += __shfl_down(l, off, 64);
        c  += __shfl_down(c, off, 64);
        np += __shfl_down(np, off, 64);
    }
    if ((tid & 63) == 0) { sl[tid >> 6] = l; sc[tid >> 6] = c; sn[tid >> 6] = np; }
    __syncthreads();
    if (tid == 0) {
        const float L = sl[0] + sl[1] + sl[2] + sl[3];
        const float C = sc[0] + sc[1] + sc[2] + sc[3];
        const float N = (float)(sn[0] + sn[1] + sn[2] + sn[3]);
        out[0] = L / N;
        out[1] = C / N;
    }
}

extern "C" void kernel_launch(void* const* d_in, const int* in_sizes, int n_in,
                              void* d_out, int out_size, void* d_ws, size_t ws_size,
                              hipStream_t stream) {
    const float* loc  = (const float*)d_in[0];
    const float* conf = (const float*)d_in[1];
    const float* arm  = (const float*)d_in[2];
    const float* loct = (const float*)d_in[3];
    const int*  conft = (const int*)d_in[4];
    float* out = (float*)d_out;

    const int total = in_sizes[4];          // B * P
    const int Bn = total / NUM_P;
    const int grid = (total + 255) / 256;

    // ws layout:
    // [0, 256):    float topk[64]
    // [256, 512):  int num_pos[64]
    // [1024, +16320):        partial_l (grid floats)
    // [33792, +16320):       partial_c
    // [66560, ...):          rankvals (16B-aligned)
    float* topk      = (float*)d_ws;
    int*   num_pos   = (int*)((char*)d_ws + 256);
    float* partial_l = (float*)((char*)d_ws + 1024);
    float* partial_c = (float*)((char*)d_ws + 33792);
    float* rankvals  = (float*)((char*)d_ws + 66560);

    hipMemsetAsync(d_ws, 0, 1024, stream);

    hipLaunchKernelGGL(anchor_kernel, dim3(grid), dim3(256), 0, stream,
                       loc, conf, arm, loct, conft, num_pos, rankvals,
                       partial_l, partial_c, total);
    hipLaunchKernelGGL(select_kernel, dim3(Bn), dim3(1024), 0, stream,
                       rankvals, num_pos, topk);
    hipLaunchKernelGGL(finalize_kernel, dim3(1), dim3(256), 0, stream,
                       topk, num_pos, partial_l, partial_c, grid, Bn, out);
}

// Round 5
// 214.883 us; speedup vs baseline: 2.7932x; 1.4672x over previous
//
#include <hip/hip_runtime.h>

#define NUM_P 16320
#define NUM_C 21
#define THETA 0.01f
#define WAVES_PER_ROW (NUM_P / 64)   // 255

// ---------------- Kernel A: per-anchor losses + pos mask (ATOMIC-FREE) -------
__global__ __launch_bounds__(256) void anchor_kernel(
    const float* __restrict__ loc, const float* __restrict__ conf,
    const float* __restrict__ arm, const float* __restrict__ loct,
    const int* __restrict__ conft,
    int* __restrict__ partial_n, float* __restrict__ rankvals,
    float* __restrict__ partial_l, float* __restrict__ partial_c, int total)
{
    __shared__ float tile[256 * NUM_C];   // 21504 B
    __shared__ float red_l[4], red_c[4];
    const int tid = threadIdx.x;
    const int base = blockIdx.x * 256;
    const int a = base + tid;

    // hoist small per-anchor loads so they overlap the staging loads
    int t = 0; float2 av = make_float2(0.f, 0.f);
    if (a < total) {
        t = conft[a];
        av = ((const float2*)arm)[a];
    }

    // register-buffered staging: all 6 float4 loads issued before any LDS write
    {
        const float4* conf4 = (const float4*)(conf + (size_t)base * NUM_C);
        const int lim = min(256 * NUM_C / 4, ((total - base) * NUM_C) / 4); // 1344 full
        float4 r[6];
        #pragma unroll
        for (int it = 0; it < 6; ++it) {
            int i = tid + it * 256;
            if (i < lim) r[it] = conf4[i];
        }
        float4* tile4 = (float4*)tile;
        #pragma unroll
        for (int it = 0; it < 6; ++it) {
            int i = tid + it * 256;
            if (i < lim) tile4[i] = r[it];
        }
    }
    __syncthreads();

    float ll = 0.f, cep = 0.f;
    bool pos = false;
    if (a < total) {
        const float* cf = &tile[tid * NUM_C];  // stride 21 -> conflict-free
        float mx = cf[0];
        #pragma unroll
        for (int j = 1; j < NUM_C; ++j) mx = fmaxf(mx, cf[j]);
        float s = 0.f;
        #pragma unroll
        for (int j = 0; j < NUM_C; ++j) s += __expf(cf[j] - mx);
        const float ce = mx + __logf(s) - cf[t];

        const float am = fmaxf(av.x, av.y);
        const float e0 = __expf(av.x - am), e1 = __expf(av.y - am);
        const float p1 = e1 / (e0 + e1);
        pos = (t > 0) && (p1 > THETA);

        if (pos) {
            cep = ce;
            const float4 lv = ((const float4*)loc)[a];
            const float4 tv = ((const float4*)loct)[a];
            const float dx[4] = { lv.x - tv.x, lv.y - tv.y, lv.z - tv.z, lv.w - tv.w };
            #pragma unroll
            for (int j = 0; j < 4; ++j) {
                float ad = fabsf(dx[j]);
                ll += (ad < 1.f) ? 0.5f * ad * ad : ad - 0.5f;
            }
        }
        rankvals[a] = pos ? 0.f : ce;          // loss_for_rank
    }

    // wave-level reduce; per-wave plain STORE of pos count (no atomics anywhere)
    unsigned long long pm = __ballot(pos);
    #pragma unroll
    for (int off = 32; off > 0; off >>= 1) {
        ll  += __shfl_down(ll, off, 64);
        cep += __shfl_down(cep, off, 64);
    }
    const int lane = tid & 63, w = tid >> 6;
    if (lane == 0) {
        red_l[w] = ll;
        red_c[w] = cep;
        if (base + (w << 6) < total)
            partial_n[blockIdx.x * 4 + w] = (int)__popcll(pm);
    }
    __syncthreads();
    if (tid == 0) {
        partial_l[blockIdx.x] = red_l[0] + red_l[1] + red_l[2] + red_l[3];
        partial_c[blockIdx.x] = red_c[0] + red_c[1] + red_c[2] + red_c[3];
    }
}

// ---------------- Kernel B: per-row radix-select top-k sum (LDS-resident) ----
// all values >= 0 so unsigned bit order == float order.
__global__ __launch_bounds__(1024) void select_kernel(
    const float* __restrict__ rankvals, const int* __restrict__ partial_n,
    float* __restrict__ topk, int* __restrict__ row_npos)
{
    __shared__ float data[NUM_P];          // 65280 B
    __shared__ int hist[256];
    __shared__ unsigned s_prefix;
    __shared__ int s_kk;
    __shared__ int s_np;
    __shared__ float wsum[16];

    const int b = blockIdx.x;
    const int tid = threadIdx.x;
    const int lane = tid & 63;

    // issue row-stage loads and the per-wave count loads up front
    const float4* row4 = (const float4*)(rankvals + (size_t)b * NUM_P);
    float4 r[4];
    #pragma unroll
    for (int it = 0; it < 4; ++it) {
        int i = tid + it * 1024;
        if (i < NUM_P / 4) r[it] = row4[i];
    }
    int rn = (tid < WAVES_PER_ROW) ? partial_n[b * WAVES_PER_ROW + tid] : 0;
    if (tid == 0) s_np = 0;
    if (tid < 256) hist[tid] = 0;
    {
        float4* d4 = (float4*)data;
        #pragma unroll
        for (int it = 0; it < 4; ++it) {
            int i = tid + it * 1024;
            if (i < NUM_P / 4) d4[i] = r[it];
        }
    }
    __syncthreads();           // s_np/hist init + data staged

    // per-wave reduce of rn, 16 atomic adds total (trivial)
    #pragma unroll
    for (int off = 32; off > 0; off >>= 1) rn += __shfl_down(rn, off, 64);
    if (lane == 0 && rn) atomicAdd(&s_np, rn);
    __syncthreads();           // np ready, hist zeroed

    const int np = s_np;
    const int k = min(3 * np, NUM_P - 1);
    if (k <= 0) {
        if (tid == 0) { topk[b] = 0.f; row_npos[b] = np; }
        return;
    }

    unsigned prefix = 0, himask = 0;
    int kk = k;

    for (int pass = 0; pass < 4; ++pass) {
        const int shift = 24 - 8 * pass;

        if (pass == 0) {
            // ballot-aggregated: exponent bytes concentrate into few bins
            for (int it = 0; it < 16; ++it) {
                const int i = tid + it * 1024;
                const bool part = i < NUM_P;
                const unsigned u = part ? __float_as_uint(data[i]) : 0u;
                const unsigned bin = u >> 24;
                unsigned long long alive = __ballot(part);
                while (alive) {
                    const int leader = __ffsll(alive) - 1;
                    const unsigned lb = __shfl(bin, leader, 64);
                    const unsigned long long mm = __ballot(part && (bin == lb));
                    if (lane == leader) atomicAdd(&hist[lb], (int)__popcll(mm));
                    alive &= ~mm;
                }
            }
        } else {
            // later passes: participants sparse/spread -> plain LDS atomics
            for (int it = 0; it < 16; ++it) {
                const int i = tid + it * 1024;
                if (i < NUM_P) {
                    const unsigned u = __float_as_uint(data[i]);
                    if ((u & himask) == prefix)
                        atomicAdd(&hist[(u >> shift) & 255u], 1);
                }
            }
        }
        __syncthreads();       // hist complete

        // wave-parallel suffix scan + bin selection (wave 0 only)
        if (tid < 64) {
            const int j0 = tid * 4;
            const int h0 = hist[j0], h1 = hist[j0 + 1], h2 = hist[j0 + 2], h3 = hist[j0 + 3];
            int ssum = h0 + h1 + h2 + h3;
            // inclusive suffix scan across lanes: ssum = sum_{l' >= lane} sums
            #pragma unroll
            for (int d = 1; d < 64; d <<= 1) {
                const int tmp = __shfl_down(ssum, d, 64);
                if (lane + d < 64) ssum += tmp;
            }
            const int bse = ssum - (h0 + h1 + h2 + h3);     // S[j0+4]
            int S[5];
            S[0] = ssum;                 // S[j0]
            S[3] = bse + h3;             // S[j0+3]
            S[2] = S[3] + h2;
            S[1] = S[2] + h1;
            S[4] = bse;
            #pragma unroll
            for (int jj = 0; jj < 4; ++jj) {
                if (S[jj] >= kk && S[jj + 1] < kk) {        // unique (S non-increasing)
                    s_prefix = prefix | ((unsigned)(j0 + jj) << shift);
                    s_kk = kk - S[jj + 1];
                }
            }
        }
        __syncthreads();       // selection visible
        prefix = s_prefix;
        kk = s_kk;
        himask |= (0xFFu << shift);
        if (tid < 256) hist[tid] = 0;   // re-zero for next pass
        __syncthreads();       // zeroing done before next pass's atomics
    }

    const unsigned vbits = prefix;       // k-th largest value (bits)
    const float vth = __uint_as_float(vbits);

    float partial = 0.f;
    for (int it = 0; it < 16; ++it) {
        const int i = tid + it * 1024;
        if (i < NUM_P) {
            const float x = data[i];
            if (__float_as_uint(x) > vbits) partial += x;
        }
    }
    #pragma unroll
    for (int off = 32; off > 0; off >>= 1)
        partial += __shfl_down(partial, off, 64);
    if (lane == 0) wsum[tid >> 6] = partial;
    __syncthreads();
    if (tid == 0) {
        float tot = 0.f;
        #pragma unroll
        for (int wv = 0; wv < 16; ++wv) tot += wsum[wv];
        // ties at the threshold contribute kk * vth (index tie-break doesn't change the sum)
        topk[b] = tot + (float)kk * vth;
        row_npos[b] = np;
    }
}

// ---------------- Kernel C: reduce partials + finalize ----------------
__global__ __launch_bounds__(256) void finalize_kernel(
    const float* __restrict__ topk, const int* __restrict__ row_npos,
    const float* __restrict__ partial_l, const float* __restrict__ partial_c,
    int nblocks, int Bn, float* __restrict__ out)
{
    __shared__ float sl[4], sc[4];
    __shared__ int sn[4];
    const int tid = threadIdx.x;
    float l = 0.f, c = 0.f;
    for (int i = tid; i < nblocks; i += 256) { l += partial_l[i]; c += partial_c[i]; }
    int np = 0;
    for (int i = tid; i < Bn; i += 256) np += row_npos[i];
    for (int i = tid; i < Bn; i += 256) c += topk[i];
    #pragma unroll
    for (int off = 32; off > 0; off >>= 1) {
        l  += __shfl_down(l, off, 64);
        c  += __shfl_down(c, off, 64);
        np += __shfl_down(np, off, 64);
    }
    if ((tid & 63) == 0) { sl[tid >> 6] = l; sc[tid >> 6] = c; sn[tid >> 6] = np; }
    __syncthreads();
    if (tid == 0) {
        const float L = sl[0] + sl[1] + sl[2] + sl[3];
        const float C = sc[0] + sc[1] + sc[2] + sc[3];
        const float N = (float)(sn[0] + sn[1] + sn[2] + sn[3]);
        out[0] = L / N;
        out[1] = C / N;
    }
}

extern "C" void kernel_launch(void* const* d_in, const int* in_sizes, int n_in,
                              void* d_out, int out_size, void* d_ws, size_t ws_size,
                              hipStream_t stream) {
    const float* loc  = (const float*)d_in[0];
    const float* conf = (const float*)d_in[1];
    const float* arm  = (const float*)d_in[2];
    const float* loct = (const float*)d_in[3];
    const int*  conft = (const int*)d_in[4];
    float* out = (float*)d_out;

    const int total = in_sizes[4];          // B * P
    const int Bn = total / NUM_P;
    const int grid = (total + 255) / 256;

    // ws layout (all regions written unconditionally every launch; no memset):
    // [0, 256):        float topk[64]
    // [256, 512):      int row_npos[64]
    // [1024, +16320):  float partial_l[grid]
    // [17408, +16320): float partial_c[grid]
    // [33792, +65280): int partial_n[grid*4]   (per-wave pos counts)
    // [99328, ...):    float rankvals[total]   (16B aligned)
    float* topk      = (float*)d_ws;
    int*   row_npos  = (int*)((char*)d_ws + 256);
    float* partial_l = (float*)((char*)d_ws + 1024);
    float* partial_c = (float*)((char*)d_ws + 17408);
    int*   partial_n = (int*)((char*)d_ws + 33792);
    float* rankvals  = (float*)((char*)d_ws + 99328);

    hipLaunchKernelGGL(anchor_kernel, dim3(grid), dim3(256), 0, stream,
                       loc, conf, arm, loct, conft, partial_n, rankvals,
                       partial_l, partial_c, total);
    hipLaunchKernelGGL(select_kernel, dim3(Bn), dim3(1024), 0, stream,
                       rankvals, partial_n, topk, row_npos);
    hipLaunchKernelGGL(finalize_kernel, dim3(1), dim3(256), 0, stream,
                       topk, row_npos, partial_l, partial_c, grid, Bn, out);
}

// Round 6
// 201.643 us; speedup vs baseline: 2.9766x; 1.0657x over previous
//
#include <hip/hip_runtime.h>

#define NUM_P 16320
#define NUM_C 21
#define THETA 0.01f
#define WAVES_PER_ROW (NUM_P / 64)   // 255

// ---------------- Kernel A: persistent, reg-prefetch double-buffered ---------
__global__ __launch_bounds__(256) void anchor_kernel(
    const float* __restrict__ loc, const float* __restrict__ conf,
    const float* __restrict__ arm, const float* __restrict__ loct,
    const int* __restrict__ conft,
    int* __restrict__ partial_n, float* __restrict__ rankvals,
    float* __restrict__ partial_l, float* __restrict__ partial_c,
    int ntiles)
{
    __shared__ float tile[256 * NUM_C];   // 21504 B
    __shared__ float red_l[4], red_c[4];
    const int tid = threadIdx.x;
    const int lane = tid & 63, w = tid >> 6;
    const int stride = gridDim.x;

    int t = blockIdx.x;
    if (t >= ntiles) return;              // uniform across block

    float4 rr[6];
    int    tc_n;
    float2 av_n;

    // prologue: load tile t into registers (total % 256 == 0, full tiles)
    {
        const int base = t * 256;
        const float4* conf4 = (const float4*)(conf + (size_t)base * NUM_C);
        #pragma unroll
        for (int it = 0; it < 6; ++it) {
            const int i = tid + it * 256;
            if (i < 1344) rr[it] = conf4[i];   // 256*21/4 = 1344
        }
        tc_n = conft[base + tid];
        av_n = ((const float2*)arm)[base + tid];
    }

    while (true) {
        const int a = t * 256 + tid;
        const int    tc = tc_n;
        const float2 av = av_n;

        // staged regs -> LDS
        {
            float4* tile4 = (float4*)tile;
            #pragma unroll
            for (int it = 0; it < 6; ++it) {
                const int i = tid + it * 256;
                if (i < 1344) tile4[i] = rr[it];
            }
        }
        __syncthreads();

        // prefetch next tile (overlaps compute below)
        const int tn = t + stride;
        if (tn < ntiles) {
            const int nbase = tn * 256;
            const float4* conf4 = (const float4*)(conf + (size_t)nbase * NUM_C);
            #pragma unroll
            for (int it = 0; it < 6; ++it) {
                const int i = tid + it * 256;
                if (i < 1344) rr[it] = conf4[i];
            }
            tc_n = conft[nbase + tid];
            av_n = ((const float2*)arm)[nbase + tid];
        }

        // compute tile t
        float ll = 0.f, cep = 0.f;
        bool pos = false;
        {
            const float* cf = &tile[tid * NUM_C];  // stride 21: conflict-free
            float mx = cf[0];
            #pragma unroll
            for (int j = 1; j < NUM_C; ++j) mx = fmaxf(mx, cf[j]);
            float s = 0.f;
            #pragma unroll
            for (int j = 0; j < NUM_C; ++j) s += __expf(cf[j] - mx);
            const float ce = mx + __logf(s) - cf[tc];

            const float am = fmaxf(av.x, av.y);
            const float e0 = __expf(av.x - am), e1 = __expf(av.y - am);
            const float p1 = e1 / (e0 + e1);
            pos = (tc > 0) && (p1 > THETA);

            if (pos) {
                cep = ce;
                const float4 lv = ((const float4*)loc)[a];
                const float4 tv = ((const float4*)loct)[a];
                const float dx[4] = { lv.x - tv.x, lv.y - tv.y, lv.z - tv.z, lv.w - tv.w };
                #pragma unroll
                for (int j = 0; j < 4; ++j) {
                    const float ad = fabsf(dx[j]);
                    ll += (ad < 1.f) ? 0.5f * ad * ad : ad - 0.5f;
                }
            }
            rankvals[a] = pos ? 0.f : ce;
        }

        // wave-level reduce; plain stores only (no atomics)
        const unsigned long long pm = __ballot(pos);
        #pragma unroll
        for (int off = 32; off > 0; off >>= 1) {
            ll  += __shfl_down(ll, off, 64);
            cep += __shfl_down(cep, off, 64);
        }
        if (lane == 0) {
            red_l[w] = ll;
            red_c[w] = cep;
            partial_n[t * 4 + w] = (int)__popcll(pm);
        }
        __syncthreads();
        if (tid == 0) {
            partial_l[t] = red_l[0] + red_l[1] + red_l[2] + red_l[3];
            partial_c[t] = red_c[0] + red_c[1] + red_c[2] + red_c[3];
        }
        if (tn >= ntiles) break;
        t = tn;
        __syncthreads();   // tile[] reads done before next iteration's writes
    }
}

// ------- Kernel B: per-row radix-select top-k sum from REGISTERS + finalize --
// all rank values >= 0 so unsigned bit order == float order.
__global__ __launch_bounds__(1024) void select_kernel(
    const float* __restrict__ rankvals, const int* __restrict__ partial_n,
    const float* __restrict__ partial_l, const float* __restrict__ partial_c,
    float* __restrict__ acc,          // [0]=L [1]=C ; ((int*)acc)[2]=N [3]=ctr
    int ntiles, float* __restrict__ out)
{
    __shared__ int hist[256];
    __shared__ unsigned s_prefix;
    __shared__ int s_kk;
    __shared__ int s_np;
    __shared__ float wsum[16], wsl[16], wsc[16];

    const int b = blockIdx.x;
    const int tid = threadIdx.x;
    const int lane = tid & 63, w = tid >> 6;

    // ---- issue all global loads up front ----
    const uint4* row4 = (const uint4*)(rankvals + (size_t)b * NUM_P);
    uint4 rr[4];
    #pragma unroll
    for (int it = 0; it < 4; ++it) {
        const int i = tid + it * 1024;
        rr[it] = (i < NUM_P / 4) ? row4[i] : make_uint4(0u, 0u, 0u, 0u);
    }
    int rn = (tid < WAVES_PER_ROW) ? partial_n[b * WAVES_PER_ROW + tid] : 0;

    float sl = 0.f, sc = 0.f;
    {
        const int slice = (ntiles + gridDim.x - 1) / gridDim.x;
        const int s0 = b * slice;
        const int s1 = min(s0 + slice, ntiles);
        for (int i = s0 + tid; i < s1; i += 1024) { sl += partial_l[i]; sc += partial_c[i]; }
    }

    if (tid == 0) s_np = 0;
    if (tid < 256) hist[tid] = 0;
    __syncthreads();

    // np reduce (waves 0-3 hold rn) + slice reduce
    #pragma unroll
    for (int off = 32; off > 0; off >>= 1) {
        rn += __shfl_down(rn, off, 64);
        sl += __shfl_down(sl, off, 64);
        sc += __shfl_down(sc, off, 64);
    }
    if (lane == 0) {
        wsl[w] = sl; wsc[w] = sc;
        if (rn) atomicAdd(&s_np, rn);
    }
    __syncthreads();

    const int np = s_np;
    const int k = min(3 * np, NUM_P - 1);

    float tot = 0.f;
    int kk = 0;
    float vth = 0.f;

    if (k > 0) {                          // block-uniform branch (syncs inside ok)
        unsigned prefix = 0, himask = 0;
        kk = k;

        for (int pass = 0; pass < 4; ++pass) {
            const int shift = 24 - 8 * pass;

            if (pass == 0) {
                // ballot-aggregated exponent histogram (few distinct bins)
                #pragma unroll
                for (int it = 0; it < 4; ++it) {
                    const unsigned ub[4] = { rr[it].x, rr[it].y, rr[it].z, rr[it].w };
                    #pragma unroll
                    for (int j = 0; j < 4; ++j) {
                        const unsigned bin = ub[j] >> 24;
                        unsigned long long alive = ~0ULL;
                        while (alive) {
                            const int leader = __ffsll(alive) - 1;
                            const unsigned lb = __shfl(bin, leader, 64);
                            const unsigned long long mm = __ballot(bin == lb);
                            if (lane == leader) atomicAdd(&hist[lb], (int)__popcll(mm));
                            alive &= ~mm;
                        }
                    }
                }
                // (out-of-range pad zeros add to bin 0; threshold never lands
                //  meaningfully there since selected values > 0 — ties at 0 add 0)
            } else {
                #pragma unroll
                for (int it = 0; it < 4; ++it) {
                    const unsigned ub[4] = { rr[it].x, rr[it].y, rr[it].z, rr[it].w };
                    #pragma unroll
                    for (int j = 0; j < 4; ++j) {
                        const unsigned u = ub[j];
                        if ((u & himask) == prefix)
                            atomicAdd(&hist[(u >> shift) & 255u], 1);
                    }
                }
            }
            __syncthreads();

            // wave-parallel suffix scan + unique bin selection (wave 0)
            if (tid < 64) {
                const int j0 = tid * 4;
                const int h0 = hist[j0], h1 = hist[j0 + 1], h2 = hist[j0 + 2], h3 = hist[j0 + 3];
                int ssum = h0 + h1 + h2 + h3;
                #pragma unroll
                for (int d = 1; d < 64; d <<= 1) {
                    const int tmp = __shfl_down(ssum, d, 64);
                    if (lane + d < 64) ssum += tmp;
                }
                const int bse = ssum - (h0 + h1 + h2 + h3);   // S[j0+4]
                int S[5];
                S[0] = ssum; S[4] = bse;
                S[3] = bse + h3; S[2] = S[3] + h2; S[1] = S[2] + h1;
                #pragma unroll
                for (int jj = 0; jj < 4; ++jj) {
                    if (S[jj] >= kk && S[jj + 1] < kk) {      // unique: S non-increasing
                        s_prefix = prefix | ((unsigned)(j0 + jj) << shift);
                        s_kk = kk - S[jj + 1];
                    }
                }
            }
            __syncthreads();
            prefix = s_prefix;
            kk = s_kk;
            himask |= (0xFFu << shift);
            if (tid < 256) hist[tid] = 0;
            __syncthreads();
        }

        const unsigned vbits = prefix;     // k-th largest value (bits)
        vth = __uint_as_float(vbits);

        float partial = 0.f;
        #pragma unroll
        for (int it = 0; it < 4; ++it) {
            const unsigned ub[4] = { rr[it].x, rr[it].y, rr[it].z, rr[it].w };
            #pragma unroll
            for (int j = 0; j < 4; ++j)
                if (ub[j] > vbits) partial += __uint_as_float(ub[j]);
        }
        #pragma unroll
        for (int off = 32; off > 0; off >>= 1)
            partial += __shfl_down(partial, off, 64);
        if (lane == 0) wsum[w] = partial;
        __syncthreads();
        if (tid == 0) {
            #pragma unroll
            for (int wv = 0; wv < 16; ++wv) tot += wsum[wv];
            tot += (float)kk * vth;        // ties at threshold
        }
    }

    // ---- per-block contribution + last-block finalize ----
    if (tid == 0) {
        float SL = 0.f, SC = 0.f;
        #pragma unroll
        for (int wv = 0; wv < 16; ++wv) { SL += wsl[wv]; SC += wsc[wv]; }
        int* acc_i = (int*)acc;
        atomicAdd(&acc[0], SL);
        atomicAdd(&acc[1], SC + tot);
        atomicAdd(&acc_i[2], np);
        __threadfence();
        const int prev = atomicAdd(&acc_i[3], 1);
        if (prev == (int)gridDim.x - 1) {
            __threadfence();
            const float L = atomicAdd(&acc[0], 0.f);
            const float C = atomicAdd(&acc[1], 0.f);
            const int   N = atomicAdd(&acc_i[2], 0);
            out[0] = L / (float)N;
            out[1] = C / (float)N;
        }
    }
}

extern "C" void kernel_launch(void* const* d_in, const int* in_sizes, int n_in,
                              void* d_out, int out_size, void* d_ws, size_t ws_size,
                              hipStream_t stream) {
    const float* loc  = (const float*)d_in[0];
    const float* conf = (const float*)d_in[1];
    const float* arm  = (const float*)d_in[2];
    const float* loct = (const float*)d_in[3];
    const int*  conft = (const int*)d_in[4];
    float* out = (float*)d_out;

    const int total  = in_sizes[4];        // B * P  (multiple of 256)
    const int Bn     = total / NUM_P;
    const int ntiles = total / 256;

    // ws layout:
    // [0,64):           float acc[2]; int acc_n; int ctr   (zeroed below)
    // [1024, +16320):   float partial_l[ntiles]
    // [17408, +16320):  float partial_c[ntiles]
    // [33792, +65280):  int partial_n[ntiles*4]
    // [99328, ...):     float rankvals[total]
    float* acc       = (float*)d_ws;
    float* partial_l = (float*)((char*)d_ws + 1024);
    float* partial_c = (float*)((char*)d_ws + 17408);
    int*   partial_n = (int*)((char*)d_ws + 33792);
    float* rankvals  = (float*)((char*)d_ws + 99328);

    hipMemsetAsync(d_ws, 0, 64, stream);

    const int grid = min(ntiles, 7 * 256);   // 7 blocks/CU (LDS-limited), persistent
    hipLaunchKernelGGL(anchor_kernel, dim3(grid), dim3(256), 0, stream,
                       loc, conf, arm, loct, conft, partial_n, rankvals,
                       partial_l, partial_c, ntiles);
    hipLaunchKernelGGL(select_kernel, dim3(Bn), dim3(1024), 0, stream,
                       rankvals, partial_n, partial_l, partial_c, acc, ntiles, out);
}